// Round 1
// baseline (251.296 us; speedup 1.0000x reference)
//
#include <hip/hip_runtime.h>
#include <hip/hip_bf16.h>
#include <cmath>

// Problem dims (fixed by reference)
#define BATCH 4
#define TLEN  4096
#define CEMB  1024
#define HEAD  64

typedef __bf16 bf16;
typedef __attribute__((ext_vector_type(8))) __bf16 bf16x8;
typedef __attribute__((ext_vector_type(4))) __bf16 bf16x4;
typedef __attribute__((ext_vector_type(4))) float f32x4;

static __device__ __forceinline__ f32x4 mfma16(bf16x8 a, bf16x8 b, f32x4 c) {
    return __builtin_amdgcn_mfma_f32_16x16x32_bf16(a, b, c, 0, 0, 0);
}

// ---------------------------------------------------------------------------
// Kernel 1: fused QKV projection.  x[16384,1024] fp32 @ {Wq,Wk,Wv}[1024,64]
// -> q,k,v bf16 [16384,64] in workspace.  Block: 256 thr = 4 waves, M-tile 64,
// N = 192 (q|k|v concatenated), K staged 32 at a time.
// MFMA frags: A[m=lane&15][k=quad*8+j], B[k=quad*8+j][n=lane&15],
// D[row=quad*4+reg][col=lane&15]  (m89/m91-verified layouts).
// ---------------------------------------------------------------------------
__global__ __launch_bounds__(256) void qkv_proj(
    const float* __restrict__ x,
    const float* __restrict__ Wq, const float* __restrict__ bq,
    const float* __restrict__ Wk, const float* __restrict__ bk,
    const float* __restrict__ Wv, const float* __restrict__ bv,
    bf16* __restrict__ qb, bf16* __restrict__ kb, bf16* __restrict__ vb)
{
    // pad rows to 40 bf16 (80 B): 16B-aligned rows for b128, banks spread
    __shared__ __align__(16) bf16 Xsh[64][40];
    __shared__ __align__(16) bf16 Wtsh[192][40];   // transposed: [n][k-chunk]

    const int tid  = threadIdx.x;
    const int lane = tid & 63;
    const int wv   = tid >> 6;        // wave id 0..3 -> M rows wv*16..
    const int quad = lane >> 4;
    const int m    = lane & 15;
    const int row0 = blockIdx.x * 64; // global M row base

    f32x4 acc[12] = {};               // 12 n-tiles of 16: q(0..3) k(4..7) v(8..11)

    const float* Ws[3] = {Wq, Wk, Wv};

    // staging index maps
    const int xr  = tid >> 2;         // 0..63   x row
    const int xc  = (tid & 3) * 8;    // 0,8,16,24
    const int wn  = tid & 63;         // 0..63   W col (n)
    const int wsg = tid >> 6;         // 0..3    k-subgroup of 8

    for (int kc = 0; kc < CEMB; kc += 32) {
        // stage x tile (coalesced 32B/lane reads, fp32 -> bf16)
        {
            const float* src = x + (size_t)(row0 + xr) * CEMB + kc + xc;
            float4 a = *(const float4*)src;
            float4 b = *(const float4*)(src + 4);
            bf16x8 v;
            v[0]=(bf16)a.x; v[1]=(bf16)a.y; v[2]=(bf16)a.z; v[3]=(bf16)a.w;
            v[4]=(bf16)b.x; v[5]=(bf16)b.y; v[6]=(bf16)b.z; v[7]=(bf16)b.w;
            *(bf16x8*)&Xsh[xr][xc] = v;
        }
        // stage W transposed: read coalesced rows, pack 8 k's, one b128 write
        #pragma unroll
        for (int wmat = 0; wmat < 3; ++wmat) {
            const float* src = Ws[wmat] + (size_t)(kc + wsg * 8) * HEAD + wn;
            bf16x8 v;
            #pragma unroll
            for (int i = 0; i < 8; ++i) v[i] = (bf16)src[i * HEAD];
            *(bf16x8*)&Wtsh[wmat * 64 + wn][wsg * 8] = v;
        }
        __syncthreads();

        bf16x8 af = *(const bf16x8*)&Xsh[wv * 16 + m][quad * 8];
        #pragma unroll
        for (int nt = 0; nt < 12; ++nt) {
            bf16x8 bfm = *(const bf16x8*)&Wtsh[nt * 16 + m][quad * 8];
            acc[nt] = mfma16(af, bfm, acc[nt]);
        }
        __syncthreads();
    }

    // epilogue: +bias, cast bf16, scattered u16 stores
    const float* bias[3] = {bq, bk, bv};
    bf16* dst[3] = {qb, kb, vb};
    #pragma unroll
    for (int nt = 0; nt < 12; ++nt) {
        const int which = nt >> 2;
        const int nh    = (nt & 3) * 16 + m;      // col = lane&15
        const float bb  = bias[which][nh];
        #pragma unroll
        for (int r = 0; r < 4; ++r) {
            const int grow = row0 + wv * 16 + quad * 4 + r;   // D row
            dst[which][(size_t)grow * HEAD + nh] = (bf16)(acc[nt][r] + bb);
        }
    }
}

// ---------------------------------------------------------------------------
// Kernel 2: flash attention.  Grid (T/64, B), block 256 = 4 waves, each wave
// owns 16 Q rows.  KV chunk = 32.  Computes S^T = K*Q^T so per-Q-row softmax
// reduction = in-lane (4 regs x 2 tiles) + shfl_xor 16/32.  P -> B-operand
// layout via wave-private LDS bounce.  O accumulated as O^T in C-layout.
// exp in base 2: logits pre-scaled by (1/sqrt(64))*log2(e).
// ---------------------------------------------------------------------------
__global__ __launch_bounds__(256) void attn(
    const bf16* __restrict__ qb, const bf16* __restrict__ kb,
    const bf16* __restrict__ vb, float* __restrict__ out)
{
    __shared__ __align__(16) bf16 Ksh[32][72];       // [s][h], pad 8
    __shared__ __align__(16) bf16 Vtsh[64][40];      // [h][s], pad 8
    __shared__ __align__(16) bf16 Psh[4][16][40];    // per-wave [q][s], pad 8

    const int tid  = threadIdx.x;
    const int lane = tid & 63;
    const int wv   = tid >> 6;
    const int quad = lane >> 4;
    const int col  = lane & 15;       // q-local index (C-layout col), also A-row m
    const int b    = blockIdx.y;
    const int q0   = blockIdx.x * 64;

    // Q fragments (B-operand of S^T mfma): row (q0+wv*16+col), contiguous k
    const size_t baseQ = ((size_t)b * TLEN + q0 + wv * 16 + col) * HEAD;
    const bf16x8 qf0 = *(const bf16x8*)(qb + baseQ + quad * 8);
    const bf16x8 qf1 = *(const bf16x8*)(qb + baseQ + 32 + quad * 8);

    f32x4 o[4] = {};                  // O^T, 4 h-tiles of 16
    float mrun = -INFINITY;
    float lrun = 0.0f;
    const float cscale = 0.125f * 1.4426950408889634f;  // 1/sqrt(64) * log2(e)

    const int kr  = tid >> 3;         // 0..31  K stage row
    const int kc  = (tid & 7) * 8;    // 0..56
    const int vh  = tid & 63;         // V stage h
    const int vsg = tid >> 6;         // s-subgroup of 8

    const bf16* kbase = kb + (size_t)b * TLEN * HEAD;
    const bf16* vbase = vb + (size_t)b * TLEN * HEAD;

    for (int s0 = 0; s0 < TLEN; s0 += 32) {
        // stage K chunk [32][64] (coalesced b128)
        *(bf16x8*)&Ksh[kr][kc] =
            *(const bf16x8*)(kbase + (size_t)(s0 + kr) * HEAD + kc);
        // stage V transposed: gather column vh over 8 s, pack, one b128 write
        {
            bf16x8 v;
            #pragma unroll
            for (int i = 0; i < 8; ++i)
                v[i] = vbase[(size_t)(s0 + vsg * 8 + i) * HEAD + vh];
            *(bf16x8*)&Vtsh[vh][vsg * 8] = v;
        }
        __syncthreads();

        // S^T tiles: A = K rows, B = Q^T  (both load as "row=lane&15, contig k")
        f32x4 st[2];
        #pragma unroll
        for (int t = 0; t < 2; ++t) {
            bf16x8 kf0 = *(const bf16x8*)&Ksh[t * 16 + col][quad * 8];
            bf16x8 kf1 = *(const bf16x8*)&Ksh[t * 16 + col][32 + quad * 8];
            f32x4 z = {0.0f, 0.0f, 0.0f, 0.0f};
            z = mfma16(kf0, qf0, z);
            z = mfma16(kf1, qf1, z);
            st[t] = z;
        }

        // logits in log2 units; online softmax per column (= per Q row)
        float L[8];
        #pragma unroll
        for (int t = 0; t < 2; ++t)
            #pragma unroll
            for (int r = 0; r < 4; ++r) L[t * 4 + r] = st[t][r] * cscale;

        float cm = L[0];
        #pragma unroll
        for (int i = 1; i < 8; ++i) cm = fmaxf(cm, L[i]);
        cm = fmaxf(cm, __shfl_xor(cm, 16, 64));
        cm = fmaxf(cm, __shfl_xor(cm, 32, 64));

        const float mnew  = fmaxf(mrun, cm);
        const float alpha = __builtin_amdgcn_exp2f(mrun - mnew);  // 0 on first chunk
        float p[8], cs = 0.0f;
        #pragma unroll
        for (int i = 0; i < 8; ++i) {
            p[i] = __builtin_amdgcn_exp2f(L[i] - mnew);
            cs += p[i];
        }
        cs += __shfl_xor(cs, 16, 64);
        cs += __shfl_xor(cs, 32, 64);
        lrun = lrun * alpha + cs;
        mrun = mnew;
        #pragma unroll
        for (int i = 0; i < 4; ++i) o[i] *= alpha;

        // P -> wave-private LDS in [q][s] layout (C-layout regs are s-contig)
        #pragma unroll
        for (int t = 0; t < 2; ++t) {
            bf16x4 pv = {(bf16)p[t*4+0], (bf16)p[t*4+1], (bf16)p[t*4+2], (bf16)p[t*4+3]};
            *(bf16x4*)&Psh[wv][col][t * 16 + quad * 4] = pv;
        }
        __threadfence_block();  // order wave-private LDS write -> read
        const bf16x8 pb = *(const bf16x8*)&Psh[wv][col][quad * 8];  // B-frag: P^T[s][q]

        // O^T += V^T * P^T  (A = V^T from transposed LDS stage)
        #pragma unroll
        for (int ht = 0; ht < 4; ++ht) {
            bf16x8 va = *(const bf16x8*)&Vtsh[ht * 16 + col][quad * 8];
            o[ht] = mfma16(va, pb, o[ht]);
        }
        __syncthreads();
    }

    // epilogue: normalize by l, store O (regs are 4 consecutive h -> dwordx4)
    const float inv_l = 1.0f / lrun;
    float* obase = out + ((size_t)b * TLEN + q0 + wv * 16 + col) * HEAD;
    #pragma unroll
    for (int ht = 0; ht < 4; ++ht) {
        f32x4 r = o[ht] * inv_l;
        *(f32x4*)(obase + ht * 16 + quad * 4) = r;
    }
}

// ---------------------------------------------------------------------------
extern "C" void kernel_launch(void* const* d_in, const int* in_sizes, int n_in,
                              void* d_out, int out_size, void* d_ws, size_t ws_size,
                              hipStream_t stream) {
    const float* x  = (const float*)d_in[0];
    const float* Wq = (const float*)d_in[1];
    const float* bq = (const float*)d_in[2];
    const float* Wk = (const float*)d_in[3];
    const float* bk = (const float*)d_in[4];
    const float* Wv = (const float*)d_in[5];
    const float* bv = (const float*)d_in[6];
    float* out = (float*)d_out;

    const size_t n_tok = (size_t)BATCH * TLEN * HEAD;  // 1,048,576
    bf16* qb = (bf16*)d_ws;
    bf16* kb = qb + n_tok;
    bf16* vb = kb + n_tok;                             // 6 MB total in d_ws

    qkv_proj<<<dim3((BATCH * TLEN) / 64), dim3(256), 0, stream>>>(
        x, Wq, bq, Wk, bk, Wv, bv, qb, kb, vb);
    attn<<<dim3(TLEN / 64, BATCH), dim3(256), 0, stream>>>(qb, kb, vb, out);
}

// Round 2
// 220.306 us; speedup vs baseline: 1.1407x; 1.1407x over previous
//
#include <hip/hip_runtime.h>
#include <hip/hip_bf16.h>
#include <cmath>

#define BATCH 4
#define TLEN  4096
#define CEMB  1024
#define HEAD  64

typedef __bf16 bf16;
typedef __attribute__((ext_vector_type(8))) __bf16 bf16x8;
typedef __attribute__((ext_vector_type(4))) __bf16 bf16x4;
typedef __attribute__((ext_vector_type(4))) float f32x4;

#define QSCALE 0.1803368801111204f   // (1/sqrt(64)) * log2(e): logits land in log2 units

static __device__ __forceinline__ f32x4 mfma16(bf16x8 a, bf16x8 b, f32x4 c) {
    return __builtin_amdgcn_mfma_f32_16x16x32_bf16(a, b, c, 0, 0, 0);
}

// ---------------------------------------------------------------------------
// Kernel 1: QKV projection, LDS-free / barrier-free.
// Wave = 16 token rows x 6 n-tiles (n-split 2 across blocks -> 8 waves/CU).
// A-frags: x rows direct from global (16 rows x 64B segments, coalesced).
// B-frags: W fp32 gathered per-lane (stride-256B, L1/L2-hot, hidden under
// the HBM x stream).  q written pre-scaled by QSCALE; v written TRANSPOSED
// vT[b][h][t] so attention can read V^T A-frags straight from global.
// ---------------------------------------------------------------------------
__global__ __launch_bounds__(256) void qkv(
    const float* __restrict__ x,
    const float* __restrict__ Wq, const float* __restrict__ bq,
    const float* __restrict__ Wk, const float* __restrict__ bk,
    const float* __restrict__ Wv, const float* __restrict__ bv,
    bf16* __restrict__ qb, bf16* __restrict__ kb, bf16* __restrict__ vT)
{
    const int tid  = threadIdx.x;
    const int lane = tid & 63;
    const int wvid = tid >> 6;
    const int quad = lane >> 4;
    const int col  = lane & 15;
    // blocks b and b+256 share rows -> same XCD (i%8) -> L2 reuse of x
    const int rt   = blockIdx.x & 255;
    const int ns   = blockIdx.x >> 8;
    const int row0 = rt * 64 + wvid * 16;

    f32x4 acc[6] = {};
    const float* xrow = x + (size_t)(row0 + col) * CEMB + quad * 8;
    const float* Wmats[3] = {Wq, Wk, Wv};

    #pragma unroll 2
    for (int kc = 0; kc < CEMB; kc += 32) {
        float4 a = *(const float4*)(xrow + kc);
        float4 c = *(const float4*)(xrow + kc + 4);
        bf16x8 af;
        af[0]=(bf16)a.x; af[1]=(bf16)a.y; af[2]=(bf16)a.z; af[3]=(bf16)a.w;
        af[4]=(bf16)c.x; af[5]=(bf16)c.y; af[6]=(bf16)c.z; af[7]=(bf16)c.w;
        #pragma unroll
        for (int j = 0; j < 6; ++j) {
            const int jg = ns * 6 + j;
            const float* W = Wmats[jg >> 2];
            const int n = (jg & 3) * 16 + col;
            const float* wp = W + (size_t)(kc + quad * 8) * HEAD + n;
            bf16x8 bfr;
            #pragma unroll
            for (int jj = 0; jj < 8; ++jj) bfr[jj] = (bf16)wp[jj * HEAD];
            acc[j] = mfma16(af, bfr, acc[j]);
        }
    }

    const float* bias[3] = {bq, bk, bv};
    #pragma unroll
    for (int j = 0; j < 6; ++j) {
        const int jg = ns * 6 + j;
        const int which = jg >> 2;
        const int h = (jg & 3) * 16 + col;
        const float bb = bias[which][h];
        if (which == 0) {            // q: pre-scaled
            #pragma unroll
            for (int r = 0; r < 4; ++r) {
                const int trow = row0 + quad * 4 + r;
                qb[(size_t)trow * HEAD + h] = (bf16)((acc[j][r] + bb) * QSCALE);
            }
        } else if (which == 1) {     // k
            #pragma unroll
            for (int r = 0; r < 4; ++r) {
                const int trow = row0 + quad * 4 + r;
                kb[(size_t)trow * HEAD + h] = (bf16)(acc[j][r] + bb);
            }
        } else {                     // v -> transposed vT[b][h][t], 4 contig t
            bf16x4 pv;
            #pragma unroll
            for (int r = 0; r < 4; ++r) pv[r] = (bf16)(acc[j][r] + bb);
            const int trow0 = row0 + quad * 4;
            const int bb_   = trow0 >> 12;
            const int tt    = trow0 & (TLEN - 1);
            *(bf16x4*)(vT + ((size_t)(bb_ * HEAD + h)) * TLEN + tt) = pv;
        }
    }
}

// ---------------------------------------------------------------------------
// Kernel 2: flash attention, barrier-free.  Wave = 32 q-rows (2 q-tiles),
// KV chunk 64, KV-split `nsplit` (flash-decoding partials).  K/V fragments
// read directly from global (shared across waves via L1/L2); only a per-wave
// LDS bounce turns P (C-layout) into the PV B-operand layout.
// S^T = K.Q^T so softmax reduction = in-lane + shfl_xor 16/32.
// ---------------------------------------------------------------------------
__global__ __launch_bounds__(256) void attn(
    const bf16* __restrict__ qb, const bf16* __restrict__ kb,
    const bf16* __restrict__ vT,
    float* __restrict__ opart, float* __restrict__ ml,
    float* __restrict__ out, int nsplit)
{
    __shared__ __align__(16) bf16 Psh[4][2][16][72];   // [wave][qt][q][s+pad]

    const int tid  = threadIdx.x;
    const int lane = tid & 63;
    const int wvid = tid >> 6;
    const int quad = lane >> 4;
    const int col  = lane & 15;
    const int b    = blockIdx.y;
    const int sp   = blockIdx.z;
    const int q0   = blockIdx.x * 128 + wvid * 32;
    const size_t rowbase = (size_t)b * TLEN + q0;

    bf16x8 qf[2][2];
    #pragma unroll
    for (int qt = 0; qt < 2; ++qt) {
        const bf16* qp = qb + (rowbase + qt * 16 + col) * HEAD + quad * 8;
        qf[qt][0] = *(const bf16x8*)qp;
        qf[qt][1] = *(const bf16x8*)(qp + 32);
    }
    const bf16* kbB = kb + (size_t)b * TLEN * HEAD;
    const bf16* vTB = vT + (size_t)b * HEAD * TLEN;

    f32x4 o[8] = {};                         // [qt*4 + ht]
    float mrun[2] = {-INFINITY, -INFINITY};
    float lrun[2] = {0.f, 0.f};

    const int slen = TLEN / nsplit;
    const int sbeg = sp * slen;

    for (int s0 = sbeg; s0 < sbeg + slen; s0 += 64) {
        // K fragments for the 64-s chunk (shared by both q-tiles)
        bf16x8 kf[4][2];
        #pragma unroll
        for (int t = 0; t < 4; ++t) {
            const bf16* kr = kbB + (size_t)(s0 + t * 16 + col) * HEAD + quad * 8;
            kf[t][0] = *(const bf16x8*)kr;
            kf[t][1] = *(const bf16x8*)(kr + 32);
        }
        #pragma unroll
        for (int qt = 0; qt < 2; ++qt) {
            f32x4 st[4];
            #pragma unroll
            for (int t = 0; t < 4; ++t) {
                f32x4 z = {0.f, 0.f, 0.f, 0.f};
                z = mfma16(kf[t][0], qf[qt][0], z);
                z = mfma16(kf[t][1], qf[qt][1], z);
                st[t] = z;
            }
            float cm = st[0][0];
            #pragma unroll
            for (int t = 0; t < 4; ++t)
                #pragma unroll
                for (int r = 0; r < 4; ++r) cm = fmaxf(cm, st[t][r]);
            cm = fmaxf(cm, __shfl_xor(cm, 16, 64));
            cm = fmaxf(cm, __shfl_xor(cm, 32, 64));
            const float mnew  = fmaxf(mrun[qt], cm);
            const float alpha = __builtin_amdgcn_exp2f(mrun[qt] - mnew);
            float p[16], cs = 0.f;
            #pragma unroll
            for (int i = 0; i < 16; ++i) {
                p[i] = __builtin_amdgcn_exp2f(st[i >> 2][i & 3] - mnew);
                cs += p[i];
            }
            cs += __shfl_xor(cs, 16, 64);
            cs += __shfl_xor(cs, 32, 64);
            lrun[qt] = lrun[qt] * alpha + cs;
            mrun[qt] = mnew;
            #pragma unroll
            for (int i = 0; i < 4; ++i) o[qt * 4 + i] *= alpha;
            #pragma unroll
            for (int t = 0; t < 4; ++t) {
                bf16x4 pv = {(bf16)p[t*4+0], (bf16)p[t*4+1],
                             (bf16)p[t*4+2], (bf16)p[t*4+3]};
                *(bf16x4*)&Psh[wvid][qt][col][t * 16 + quad * 4] = pv;
            }
        }
        asm volatile("s_waitcnt lgkmcnt(0)" ::: "memory");
        bf16x8 pb[2][2];
        #pragma unroll
        for (int qt = 0; qt < 2; ++qt) {
            pb[qt][0] = *(const bf16x8*)&Psh[wvid][qt][col][quad * 8];
            pb[qt][1] = *(const bf16x8*)&Psh[wvid][qt][col][32 + quad * 8];
        }
        #pragma unroll
        for (int ht = 0; ht < 4; ++ht) {
            const bf16* vr = vTB + (size_t)(ht * 16 + col) * TLEN + s0 + quad * 8;
            bf16x8 v0 = *(const bf16x8*)vr;
            bf16x8 v1 = *(const bf16x8*)(vr + 32);
            o[ht]     = mfma16(v0, pb[0][0], o[ht]);
            o[ht]     = mfma16(v1, pb[0][1], o[ht]);
            o[4 + ht] = mfma16(v0, pb[1][0], o[4 + ht]);
            o[4 + ht] = mfma16(v1, pb[1][1], o[4 + ht]);
        }
        asm volatile("s_waitcnt lgkmcnt(0)" ::: "memory");  // pb reads done before next-iter P writes
    }

    #pragma unroll
    for (int qt = 0; qt < 2; ++qt) {
        const size_t grow = rowbase + qt * 16 + col;
        if (nsplit == 1) {
            const float inv = 1.f / lrun[qt];
            float* ob = out + grow * HEAD;
            #pragma unroll
            for (int ht = 0; ht < 4; ++ht) {
                f32x4 r = o[qt * 4 + ht] * inv;
                *(f32x4*)(ob + ht * 16 + quad * 4) = r;
            }
        } else {
            const size_t NR = (size_t)BATCH * TLEN;
            float* ob = opart + ((size_t)sp * NR + grow) * HEAD;
            #pragma unroll
            for (int ht = 0; ht < 4; ++ht)
                *(f32x4*)(ob + ht * 16 + quad * 4) = o[qt * 4 + ht];
            if (quad == 0) {
                float2 v2 = make_float2(mrun[qt], lrun[qt]);
                *(float2*)(ml + ((size_t)sp * NR + grow) * 2) = v2;
            }
        }
    }
}

// ---------------------------------------------------------------------------
// Kernel 3: combine KV-split partials.  thread = (row, 4 h)
// out = sum_s exp2(m_s - M) o_s / sum_s exp2(m_s - M) l_s
// ---------------------------------------------------------------------------
__global__ __launch_bounds__(256) void combine(
    const float* __restrict__ opart, const float* __restrict__ ml,
    float* __restrict__ out, int nsplit)
{
    const int gid = blockIdx.x * 256 + threadIdx.x;
    const int row = gid >> 4;
    const int h4  = (gid & 15) * 4;
    const size_t NR = (size_t)BATCH * TLEN;

    float M = -INFINITY;
    for (int s = 0; s < nsplit; ++s)
        M = fmaxf(M, ml[((size_t)s * NR + row) * 2]);
    f32x4 O = {};
    float L = 0.f;
    for (int s = 0; s < nsplit; ++s) {
        const float* mlp = ml + ((size_t)s * NR + row) * 2;
        const float w = __builtin_amdgcn_exp2f(mlp[0] - M);
        L += w * mlp[1];
        f32x4 ov = *(const f32x4*)(opart + ((size_t)s * NR + row) * HEAD + h4);
        O += ov * w;
    }
    f32x4 r = O * (1.f / L);
    *(f32x4*)(out + (size_t)row * HEAD + h4) = r;
}

// ---------------------------------------------------------------------------
extern "C" void kernel_launch(void* const* d_in, const int* in_sizes, int n_in,
                              void* d_out, int out_size, void* d_ws, size_t ws_size,
                              hipStream_t stream) {
    const float* x  = (const float*)d_in[0];
    const float* Wq = (const float*)d_in[1];
    const float* bq = (const float*)d_in[2];
    const float* Wk = (const float*)d_in[3];
    const float* bk = (const float*)d_in[4];
    const float* Wv = (const float*)d_in[5];
    const float* bv = (const float*)d_in[6];
    float* out = (float*)d_out;

    const size_t n_tok = (size_t)BATCH * TLEN * HEAD;   // 1,048,576
    char* ws = (char*)d_ws;
    bf16* qb = (bf16*)ws;
    bf16* kb = qb + n_tok;
    bf16* vT = kb + n_tok;
    const size_t base = 3 * n_tok * sizeof(bf16);       // 6 MB
    const size_t per  = n_tok * sizeof(float)           // opart: 4 MB / split
                      + (size_t)BATCH * TLEN * 2 * sizeof(float); // ml: 128 KB / split

    int S = 1;                                           // ws_size is constant across calls
    if      (ws_size >= base + 4 * per) S = 4;
    else if (ws_size >= base + 2 * per) S = 2;
    float* opart = (float*)(ws + base);
    float* mlp   = (float*)(ws + base + (size_t)S * n_tok * sizeof(float));

    qkv<<<dim3(512), dim3(256), 0, stream>>>(x, Wq, bq, Wk, bk, Wv, bv, qb, kb, vT);
    attn<<<dim3(TLEN / 128, BATCH, S), dim3(256), 0, stream>>>(
        qb, kb, vT, opart, mlp, out, S);
    if (S > 1)
        combine<<<dim3((BATCH * TLEN * 16) / 256), dim3(256), 0, stream>>>(
            opart, mlp, out, S);
}